// Round 9
// baseline (317.988 us; speedup 1.0000x reference)
//
#include <hip/hip_runtime.h>
#include <hip/hip_bf16.h>

using bf16x8  = __attribute__((ext_vector_type(8))) short;
using f32x2   = __attribute__((ext_vector_type(2))) float;
using f32x4   = __attribute__((ext_vector_type(4))) float;
using ushort8 = __attribute__((ext_vector_type(8))) unsigned short;

#define BB   32
#define CIN  128
#define COUT 128
#define PODS 2
#define HIN  56
#define WIN  56
#define HW   4096   // 64*64 padded spatial, natural [kh][kw] flat index
#define GRID 512
#define TPB  256

__device__ __forceinline__ unsigned short bf16bits(float v) {
  __hip_bfloat16 h = __float2bfloat16(v);
  return reinterpret_cast<unsigned short&>(h);
}
__device__ __forceinline__ float bits2f(unsigned short u) {
  return __uint_as_float(((unsigned)u) << 16);
}

// 64-pt FWHT on 32 x f32x2 (value w lives at a[w>>1][w&1]).
__device__ __forceinline__ void fwht64v(f32x2 (&a)[32]) {
  #pragma unroll
  for (int i = 0; i < 32; ++i) {
    float u = a[i][0], v = a[i][1];
    a[i][0] = u + v; a[i][1] = u - v;
  }
  #pragma unroll
  for (int d = 1; d <= 16; d <<= 1) {
    #pragma unroll
    for (int i = 0; i < 32; i += 2*d) {
      #pragma unroll
      for (int j = 0; j < d; ++j) {
        f32x2 u = a[i+j], v = a[i+j+d];
        a[i+j]   = u + v;
        a[i+j+d] = u - v;
      }
    }
  }
}

#define LDS_WAIT() asm volatile("s_waitcnt lgkmcnt(0)" ::: "memory")

// Manual grid barrier (persistent kernel; all GRID blocks co-resident by
// capacity arithmetic). Release: per-thread device-scope fence, block sync,
// thread0 device-atomic signal. Acquire: spin on atomic RMW (coherent point),
// then fence.
__device__ __forceinline__ void grid_barrier(unsigned* cnt, unsigned target) {
  __threadfence();
  __syncthreads();
  if (threadIdx.x == 0) {
    atomicAdd(cnt, 1u);
    while (atomicAdd(cnt, 0u) < target) {
      __builtin_amdgcn_s_sleep(2);
    }
  }
  __syncthreads();
  __threadfence();
}

// ---- phase 1 body: forward 2D FWHT of tile bc (wave-local, 9216B LDS region)
__device__ __forceinline__ void fwd_tile(const float* __restrict__ x,
                                         unsigned short* __restrict__ F,
                                         char* sm, int bc, int lane) {
  f32x2 av[32];
  #pragma unroll
  for (int i = 0; i < 32; ++i) av[i] = (f32x2){0.f, 0.f};
  if (lane < WIN) {
    const float* xp = x + (size_t)bc*(HIN*WIN) + lane;
    #pragma unroll
    for (int h = 0; h < HIN; ++h) av[h>>1][h&1] = xp[h*WIN];
  }

  fwht64v(av);                                 // over h (lane owns w=lane)

  #pragma unroll
  for (int k = 0; k < 64; ++k)
    *reinterpret_cast<unsigned short*>(&sm[k*144 + lane*2]) = bf16bits(av[k>>1][k&1]);
  LDS_WAIT();
  #pragma unroll
  for (int c = 0; c < 8; ++c) {
    ushort8 v = *reinterpret_cast<const ushort8*>(&sm[lane*144 + c*16]);
    #pragma unroll
    for (int e = 0; e < 8; ++e) av[c*4 + (e>>1)][e&1] = bits2f(v[e]);
  }
  LDS_WAIT();

  fwht64v(av);                                 // over w (lane owns kh=lane)

  #pragma unroll
  for (int j = 0; j < 8; ++j) {
    ushort8 v;
    #pragma unroll
    for (int e = 0; e < 8; ++e) v[e] = bf16bits(av[j*4 + (e>>1)][e&1]);
    *reinterpret_cast<ushort8*>(&sm[lane*144 + j*16]) = v;
  }
  LDS_WAIT();

  unsigned short* Fp = F + (size_t)bc * HW;
  #pragma unroll
  for (int jj = 0; jj < 8; ++jj) {
    int r = jj*8 + (lane >> 3);
    ushort8 v = *reinterpret_cast<const ushort8*>(&sm[r*144 + (lane & 7)*16]);
    *reinterpret_cast<ushort8*>(Fp + jj*512 + lane*8) = v;
  }
}

// ---- phase 3 body: inverse 2D FWHT of tile bo: y = crop(IWHT(G+F))/4096
__device__ __forceinline__ void inv_tile(const unsigned short* __restrict__ G,
                                         const unsigned short* __restrict__ F,
                                         float* __restrict__ y,
                                         char* sm, int bo, int lane) {
  const unsigned short* Gp = G + (size_t)bo * HW;
  const unsigned short* Fp = F + (size_t)bo * HW;
  #pragma unroll
  for (int jj = 0; jj < 8; ++jj) {
    ushort8 g = *reinterpret_cast<const ushort8*>(Gp + jj*512 + lane*8);
    ushort8 f = *reinterpret_cast<const ushort8*>(Fp + jj*512 + lane*8);
    int kh = jj*8 + (lane >> 3);
    ushort8 s;
    #pragma unroll
    for (int e = 0; e < 8; ++e) s[e] = bf16bits(bits2f(g[e]) + bits2f(f[e]));
    *reinterpret_cast<ushort8*>(&sm[kh*144 + (lane & 7)*16]) = s;
  }
  LDS_WAIT();

  f32x2 av[32];
  #pragma unroll
  for (int k = 0; k < 64; ++k)
    av[k>>1][k&1] = bits2f(*reinterpret_cast<const unsigned short*>(&sm[k*144 + lane*2]));
  LDS_WAIT();

  fwht64v(av);                                 // over kh

  #pragma unroll
  for (int h = 0; h < 64; ++h)
    *reinterpret_cast<unsigned short*>(&sm[h*144 + lane*2]) = bf16bits(av[h>>1][h&1]);
  LDS_WAIT();
  #pragma unroll
  for (int c = 0; c < 8; ++c) {
    ushort8 v = *reinterpret_cast<const ushort8*>(&sm[lane*144 + c*16]);
    #pragma unroll
    for (int e = 0; e < 8; ++e) av[c*4 + (e>>1)][e&1] = bits2f(v[e]);
  }
  LDS_WAIT();

  fwht64v(av);                                 // over kw -> y row h=lane

  #pragma unroll
  for (int i = 0; i < 32; ++i) av[i] *= (1.f/4096.f);

  float (*tf)[72] = reinterpret_cast<float(*)[72]>(sm);
  float* yp = y + (size_t)bo*(HIN*WIN) + lane;

  if (lane < 32) {
    #pragma unroll
    for (int w4 = 0; w4 < 16; ++w4) {
      float4 v = {av[w4*2][0], av[w4*2][1], av[w4*2+1][0], av[w4*2+1][1]};
      *reinterpret_cast<float4*>(&tf[lane][w4*4]) = v;
    }
  }
  LDS_WAIT();
  if (lane < WIN) {
    #pragma unroll
    for (int h = 0; h < 32; ++h) yp[h*WIN] = tf[h][lane];
  }
  LDS_WAIT();
  if (lane >= 32 && lane < HIN) {
    #pragma unroll
    for (int w4 = 0; w4 < 16; ++w4) {
      float4 v = {av[w4*2][0], av[w4*2][1], av[w4*2+1][0], av[w4*2+1][1]};
      *reinterpret_cast<float4*>(&tf[lane - 32][w4*4]) = v;
    }
  }
  LDS_WAIT();
  if (lane < WIN) {
    #pragma unroll
    for (int h = 32; h < HIN; ++h) yp[h*WIN] = tf[h - 32][lane];
  }
}

// ---- fused persistent kernel: fwd (x8/blk) | gridbar | mix (x2/blk) |
//      gridbar | ifwht (x8/blk)
__global__ __launch_bounds__(TPB, 2) void k_fused(const float* __restrict__ x,
                                                  const float* __restrict__ cw,
                                                  const float* __restrict__ lv,
                                                  const float* __restrict__ T,
                                                  unsigned short* __restrict__ F,
                                                  unsigned short* __restrict__ G,
                                                  float* __restrict__ y,
                                                  unsigned* __restrict__ bar) {
  __shared__ __align__(16) char smem[4*9216];   // 36.9 KB; phase2 uses 33.8 KB
  const int tid  = threadIdx.x;
  const int wv   = tid >> 6;
  const int lane = tid & 63;
  const int blk  = blockIdx.x;

  // ================= phase 1: forward FWHT (4096 tiles) =================
  {
    char* sm = smem + wv*9216;
    fwd_tile(x, F, sm, blk*8 + wv*2 + 0, lane);
    fwd_tile(x, F, sm, blk*8 + wv*2 + 1, lane);
  }
  grid_barrier(bar, GRID);

  // ================= phase 2: mix (1024 units) =================
  {
    char* FT = smem;                                    // 32768 B
    float (*ev)[128] = reinterpret_cast<float(*)[128]>(smem + 32768);

    // A fragments + thresholds: unit-independent, load once
    bf16x8 afr[PODS][2][4];
    {
      const int g8 = (lane >> 4) * 8;
      #pragma unroll
      for (int p = 0; p < PODS; ++p)
        #pragma unroll
        for (int tm = 0; tm < 2; ++tm)
          #pragma unroll
          for (int kk = 0; kk < 4; ++kk) {
            int o = wv*32 + tm*16 + (lane & 15);
            const float* wp = cw + ((size_t)(p*COUT + o))*CIN + kk*32 + g8;
            float4 w0 = *reinterpret_cast<const float4*>(wp);
            float4 w1 = *reinterpret_cast<const float4*>(wp + 4);
            bf16x8 fr;
            fr[0] = (short)bf16bits(w0.x); fr[1] = (short)bf16bits(w0.y);
            fr[2] = (short)bf16bits(w0.z); fr[3] = (short)bf16bits(w0.w);
            fr[4] = (short)bf16bits(w1.x); fr[5] = (short)bf16bits(w1.y);
            fr[6] = (short)bf16bits(w1.z); fr[7] = (short)bf16bits(w1.w);
            afr[p][tm][kk] = fr;
          }
    }
    float th[2][4];
    #pragma unroll
    for (int tm = 0; tm < 2; ++tm)
      #pragma unroll
      for (int r = 0; r < 4; ++r)
        th[tm][r] = fmaxf(T[wv*32 + tm*16 + (lane >> 4)*4 + r], 0.f);

    for (int rep = 0; rep < 2; ++rep) {
      const int unit = blk*2 + rep;
      const int b    = unit >> 5;
      const int hwb  = unit & 31;

      if (rep) __syncthreads();     // prior rep's FT reads complete

      { // ev table
        int p = tid >> 7, h = tid & 127;
        ev[p][h] = expf(lv[p*HW + hwb*128 + h]);
      }
      { // stage FT: lane owns hw rows {2l,2l+1}, wave owns i-range wv*32..+31
        const unsigned short* Fb = F + (size_t)b*CIN*HW + hwb*128 + 2*lane;
        const int i0w = wv*32;
        unsigned uu[32];
        #pragma unroll
        for (int i = 0; i < 32; ++i)
          uu[i] = *reinterpret_cast<const unsigned*>(Fb + (size_t)(i0w + i)*HW);
        const int r0 = 2*lane, r1 = 2*lane + 1;
        #pragma unroll
        for (int m = 0; m < 4; ++m) {
          ushort8 v0, v1;
          #pragma unroll
          for (int e = 0; e < 8; ++e) {
            unsigned u = uu[m*8 + e];
            v0[e] = (unsigned short)(u & 0xffffu);
            v1[e] = (unsigned short)(u >> 16);
          }
          int colb = wv*64 + m*16;
          *reinterpret_cast<ushort8*>(&FT[r0*256 + (colb ^ ((r0&15)<<4))]) = v0;
          *reinterpret_cast<ushort8*>(&FT[r1*256 + (colb ^ ((r1&15)<<4))]) = v1;
        }
      }
      __syncthreads();

      unsigned short* Gb = G + (size_t)b * COUT * HW + hwb*128;
      #pragma unroll
      for (int t = 0; t < 8; ++t) {
        f32x4 acc[2][2];  // [tm][pod]
        #pragma unroll
        for (int tm = 0; tm < 2; ++tm)
          #pragma unroll
          for (int p = 0; p < PODS; ++p)
            acc[tm][p] = (f32x4){0.f, 0.f, 0.f, 0.f};

        const int row = t*16 + (lane & 15);
        const int rb  = row << 8;
        const int sw  = (row & 15) << 4;
        #pragma unroll
        for (int kk = 0; kk < 4; ++kk) {
          int cb = (kk*64 + (lane >> 4)*16) ^ sw;
          bf16x8 bfrag = *reinterpret_cast<const bf16x8*>(&FT[rb + cb]);
          #pragma unroll
          for (int tm = 0; tm < 2; ++tm) {
            acc[tm][0] = __builtin_amdgcn_mfma_f32_16x16x32_bf16(afr[0][tm][kk], bfrag, acc[tm][0], 0, 0, 0);
            acc[tm][1] = __builtin_amdgcn_mfma_f32_16x16x32_bf16(afr[1][tm][kk], bfrag, acc[tm][1], 0, 0, 0);
          }
        }

        const float v0 = ev[0][t*16 + (lane & 15)];
        const float v1 = ev[1][t*16 + (lane & 15)];
        #pragma unroll
        for (int tm = 0; tm < 2; ++tm) {
          #pragma unroll
          for (int r = 0; r < 4; ++r) {
            float f = v0*acc[tm][0][r] + v1*acc[tm][1][r];
            float m = fabsf(f) - th[tm][r];
            m = m > 0.f ? m : 0.f;
            int o = wv*32 + tm*16 + (lane >> 4)*4 + r;
            Gb[(size_t)o*HW + t*16 + (lane & 15)] = bf16bits(copysignf(m, f));
          }
        }
      }
    }
  }
  grid_barrier(bar, 2*GRID);

  // ================= phase 3: inverse FWHT (4096 tiles) =================
  {
    char* sm = smem + wv*9216;
    inv_tile(G, F, y, sm, blk*8 + wv*2 + 0, lane);
    inv_tile(G, F, y, sm, blk*8 + wv*2 + 1, lane);
  }
}

extern "C" void kernel_launch(void* const* d_in, const int* in_sizes, int n_in,
                              void* d_out, int out_size, void* d_ws, size_t ws_size,
                              hipStream_t stream) {
  const float* x  = (const float*)d_in[0];
  const float* cw = (const float*)d_in[1];
  const float* lv = (const float*)d_in[2];
  const float* T  = (const float*)d_in[3];
  float* y = (float*)d_out;

  char* ws = (char*)d_ws;
  const size_t szF = (size_t)BB * CIN * HW * 2;   // 33.5 MB
  const size_t szG = (size_t)BB * COUT * HW * 2;  // 33.5 MB

  unsigned short* F   = (unsigned short*)ws;
  unsigned short* G   = (unsigned short*)(ws + szF);
  unsigned*       bar = (unsigned*)(ws + szF + szG);
  (void)ws_size;

  // zero the barrier counter every call (deterministic across graph replays)
  hipMemsetAsync(bar, 0, sizeof(unsigned), stream);

  k_fused<<<dim3(GRID), dim3(TPB), 0, stream>>>(x, cw, lv, T, F, G, y, bar);
}